// Round 1
// baseline (594.166 us; speedup 1.0000x reference)
//
#include <hip/hip_runtime.h>

typedef short bf16x8 __attribute__((ext_vector_type(8)));
typedef unsigned short u16x8 __attribute__((ext_vector_type(8)));
typedef float f32x4 __attribute__((ext_vector_type(4)));
typedef unsigned short u16;

#define MFMA16(a, b, c) __builtin_amdgcn_mfma_f32_16x16x32_bf16((a), (b), (c), 0, 0, 0)

__device__ __forceinline__ u16 bf16_rtn(float f) {
  unsigned u = __float_as_uint(f);
  u += 0x7fffu + ((u >> 16) & 1u);
  return (u16)(u >> 16);
}
__device__ __forceinline__ float bf16_to_f(u16 h) {
  return __uint_as_float(((unsigned)h) << 16);
}
__device__ __forceinline__ void splitf(float f, u16& hi, u16& lo) {
  hi = bf16_rtn(f);
  lo = bf16_rtn(f - bf16_to_f(hi));
}

// ---------------- elementwise convert ----------------
__global__ void k_split(const float* __restrict__ in, u16* __restrict__ hi,
                        u16* __restrict__ lo, int n4) {
  int i = blockIdx.x * blockDim.x + threadIdx.x;
  if (i >= n4) return;
  float4 v = ((const float4*)in)[i];
  ushort4 h, l;
  splitf(v.x, h.x, l.x);
  splitf(v.y, h.y, l.y);
  splitf(v.z, h.z, l.z);
  splitf(v.w, h.w, l.w);
  ((ushort4*)hi)[i] = h;
  ((ushort4*)lo)[i] = l;
}

__global__ void k_conv(const float* __restrict__ in, u16* __restrict__ hi, int n4) {
  int i = blockIdx.x * blockDim.x + threadIdx.x;
  if (i >= n4) return;
  float4 v = ((const float4*)in)[i];
  ushort4 h;
  h.x = bf16_rtn(v.x);
  h.y = bf16_rtn(v.y);
  h.z = bf16_rtn(v.z);
  h.w = bf16_rtn(v.w);
  ((ushort4*)hi)[i] = h;
}

// ------------- transpose fp32 [R][C] -> bf16 [C][R] (hi / hi+lo) -------------
template <int SPLIT>
__global__ void k_tconv(const float* __restrict__ in, u16* __restrict__ hi,
                        u16* __restrict__ lo, int R, int C) {
  __shared__ float tile[32][33];
  int c0 = blockIdx.x * 32, r0 = blockIdx.y * 32;
  int tx = threadIdx.x & 31, ty = threadIdx.x >> 5;
#pragma unroll
  for (int i = 0; i < 4; ++i)
    tile[ty + i * 8][tx] = in[(size_t)(r0 + ty + i * 8) * C + c0 + tx];
  __syncthreads();
#pragma unroll
  for (int i = 0; i < 4; ++i) {
    float v = tile[tx][ty + i * 8];
    size_t o = (size_t)(c0 + ty + i * 8) * R + r0 + tx;
    if (SPLIT) {
      u16 h, l;
      splitf(v, h, l);
      hi[o] = h;
      lo[o] = l;
    } else {
      hi[o] = bf16_rtn(v);
    }
  }
}

// ------------- transpose u16 [R][C] -> [C][R], batched over z -------------
__global__ void k_t16(const u16* __restrict__ in, u16* __restrict__ out, int R, int C) {
  size_t base = (size_t)blockIdx.z * R * C;
  __shared__ u16 tile[32][33];
  int c0 = blockIdx.x * 32, r0 = blockIdx.y * 32;
  int tx = threadIdx.x & 31, ty = threadIdx.x >> 5;
#pragma unroll
  for (int i = 0; i < 4; ++i)
    tile[ty + i * 8][tx] = in[base + (size_t)(r0 + ty + i * 8) * C + c0 + tx];
  __syncthreads();
#pragma unroll
  for (int i = 0; i < 4; ++i)
    out[base + (size_t)(c0 + ty + i * 8) * R + r0 + tx] = tile[tx][ty + i * 8];
}

// ------------- GEMM: C[M,Nc] = A[M,K] * B[Nc,K]^T + bias -------------
// A, B given as bf16 (hi and optional lo for split-precision 3-pass MFMA).
template <int SPLIT, int GELU, int OUTBF>
__global__ __launch_bounds__(256) void k_gemm(
    const u16* __restrict__ Ahi, const u16* __restrict__ Alo,
    const u16* __restrict__ Bhi, const u16* __restrict__ Blo,
    const float* __restrict__ bias, void* __restrict__ Cout,
    int M, int Nc, int K) {
  extern __shared__ u16 sm[];
  const int LDT = 40;  // 32 + 8 pad -> 16B-aligned rows, 2-way-max bank conflict
  u16* lA = sm;
  u16* lB = sm + 128 * LDT;
  u16* lAl = SPLIT ? sm + 2 * 128 * LDT : (u16*)nullptr;
  u16* lBl = SPLIT ? sm + 3 * 128 * LDT : (u16*)nullptr;

  int t = threadIdx.x;
  int m0 = blockIdx.y * 128, n0 = blockIdx.x * 128;
  int lane = t & 63, w = t >> 6;
  int wr = (w >> 1) * 64, wc = (w & 1) * 64;
  int li = lane & 15, g = lane >> 4;
  int srow = t >> 1, sk = (t & 1) * 16;

  f32x4 acc[4][4] = {};

  const int nk = K >> 5;
  for (int kb = 0; kb < nk; ++kb) {
    int k0 = kb * 32;
    {
      const u16* ga = Ahi + (size_t)(m0 + srow) * K + k0 + sk;
      const u16* gb = Bhi + (size_t)(n0 + srow) * K + k0 + sk;
      *(u16x8*)&lA[srow * LDT + sk] = *(const u16x8*)ga;
      *(u16x8*)&lA[srow * LDT + sk + 8] = *(const u16x8*)(ga + 8);
      *(u16x8*)&lB[srow * LDT + sk] = *(const u16x8*)gb;
      *(u16x8*)&lB[srow * LDT + sk + 8] = *(const u16x8*)(gb + 8);
      if (SPLIT) {
        const u16* gal = Alo + (size_t)(m0 + srow) * K + k0 + sk;
        const u16* gbl = Blo + (size_t)(n0 + srow) * K + k0 + sk;
        *(u16x8*)&lAl[srow * LDT + sk] = *(const u16x8*)gal;
        *(u16x8*)&lAl[srow * LDT + sk + 8] = *(const u16x8*)(gal + 8);
        *(u16x8*)&lBl[srow * LDT + sk] = *(const u16x8*)gbl;
        *(u16x8*)&lBl[srow * LDT + sk + 8] = *(const u16x8*)(gbl + 8);
      }
    }
    __syncthreads();
    bf16x8 af[4], bfr[4], afl[4], bfl[4];
#pragma unroll
    for (int i = 0; i < 4; ++i) {
      af[i] = *(const bf16x8*)&lA[(wr + i * 16 + li) * LDT + g * 8];
      bfr[i] = *(const bf16x8*)&lB[(wc + i * 16 + li) * LDT + g * 8];
      if (SPLIT) {
        afl[i] = *(const bf16x8*)&lAl[(wr + i * 16 + li) * LDT + g * 8];
        bfl[i] = *(const bf16x8*)&lBl[(wc + i * 16 + li) * LDT + g * 8];
      }
    }
#pragma unroll
    for (int a = 0; a < 4; ++a)
#pragma unroll
      for (int b = 0; b < 4; ++b) {
        acc[a][b] = MFMA16(af[a], bfr[b], acc[a][b]);
        if (SPLIT) {
          acc[a][b] = MFMA16(af[a], bfl[b], acc[a][b]);
          acc[a][b] = MFMA16(afl[a], bfr[b], acc[a][b]);
        }
      }
    __syncthreads();
  }

#pragma unroll
  for (int a = 0; a < 4; ++a)
#pragma unroll
    for (int b = 0; b < 4; ++b)
#pragma unroll
      for (int r = 0; r < 4; ++r) {
        int row = m0 + wr + a * 16 + g * 4 + r;
        int col = n0 + wc + b * 16 + li;
        float v = acc[a][b][r] + bias[col];
        if (GELU) v = 0.5f * v * (1.0f + erff(v * 0.70710678118654752f));
        if (OUTBF)
          ((u16*)Cout)[(size_t)row * Nc + col] = bf16_rtn(v);
        else
          ((float*)Cout)[(size_t)row * Nc + col] = v;
      }
}

// ------------- flash attention, strictly-causal + [0,0], no 1/sqrt(d) -------------
// grid: (qb=T/64, H, N); block 256 (4 waves, 16 q-rows each)
__global__ __launch_bounds__(256) void k_attn(
    const float* __restrict__ qf, const float* __restrict__ kf,
    const u16* __restrict__ VT, u16* __restrict__ out) {
  const int T = 2048, E = 1024, HD = 64, H = 16;
  int qb = blockIdx.x, h = blockIdx.y, n = blockIdx.z;
  __shared__ u16 Qh[64][72], Ql[64][72], Kh[64][72], Kl[64][72], P[64][72];
  int t = threadIdx.x, lane = t & 63, w = t >> 6;
  int li = lane & 15, g = lane >> 4;

  {  // stage Q block (fp32 -> hi/lo bf16)
    int row = t >> 2, c0 = (t & 3) * 16;
    const float* src = qf + (size_t)(n * T + qb * 64 + row) * E + h * HD + c0;
#pragma unroll
    for (int f = 0; f < 4; ++f) {
      float4 v = *(const float4*)(src + f * 4);
      ushort4 hh, ll;
      splitf(v.x, hh.x, ll.x);
      splitf(v.y, hh.y, ll.y);
      splitf(v.z, hh.z, ll.z);
      splitf(v.w, hh.w, ll.w);
      *(ushort4*)&Qh[row][c0 + f * 4] = hh;
      *(ushort4*)&Ql[row][c0 + f * 4] = ll;
    }
  }
  __syncthreads();
  bf16x8 qh[2], ql[2];
#pragma unroll
  for (int ks = 0; ks < 2; ++ks) {
    qh[ks] = *(const bf16x8*)&Qh[w * 16 + li][ks * 32 + g * 8];
    ql[ks] = *(const bf16x8*)&Ql[w * 16 + li][ks * 32 + g * 8];
  }

  float mr[4] = {-INFINITY, -INFINITY, -INFINITY, -INFINITY};
  float lr[4] = {0.f, 0.f, 0.f, 0.f};
  f32x4 O[4] = {};
  const u16* vtb = VT + (size_t)(n * H + h) * HD * T;

  for (int kb = 0; kb <= qb; ++kb) {
    {  // stage K block
      int row = t >> 2, c0 = (t & 3) * 16;
      const float* src = kf + (size_t)(n * T + kb * 64 + row) * E + h * HD + c0;
#pragma unroll
      for (int f = 0; f < 4; ++f) {
        float4 v = *(const float4*)(src + f * 4);
        ushort4 hh, ll;
        splitf(v.x, hh.x, ll.x);
        splitf(v.y, hh.y, ll.y);
        splitf(v.z, hh.z, ll.z);
        splitf(v.w, hh.w, ll.w);
        *(ushort4*)&Kh[row][c0 + f * 4] = hh;
        *(ushort4*)&Kl[row][c0 + f * 4] = ll;
      }
    }
    __syncthreads();

    f32x4 s[4] = {};
#pragma unroll
    for (int ks = 0; ks < 2; ++ks)
#pragma unroll
      for (int c = 0; c < 4; ++c) {
        bf16x8 kh = *(const bf16x8*)&Kh[c * 16 + li][ks * 32 + g * 8];
        bf16x8 kl = *(const bf16x8*)&Kl[c * 16 + li][ks * 32 + g * 8];
        s[c] = MFMA16(qh[ks], kh, s[c]);
        s[c] = MFMA16(qh[ks], kl, s[c]);
        s[c] = MFMA16(ql[ks], kh, s[c]);
      }

    if (kb == qb) {
#pragma unroll
      for (int c = 0; c < 4; ++c)
#pragma unroll
        for (int r = 0; r < 4; ++r) {
          int i = qb * 64 + w * 16 + g * 4 + r;
          int j = kb * 64 + c * 16 + li;
          if (!(j < i || (i == 0 && j == 0))) s[c][r] = -INFINITY;
        }
    }

    float ml[4];
#pragma unroll
    for (int r = 0; r < 4; ++r)
      ml[r] = fmaxf(fmaxf(s[0][r], s[1][r]), fmaxf(s[2][r], s[3][r]));
#pragma unroll
    for (int off = 1; off < 16; off <<= 1)
#pragma unroll
      for (int r = 0; r < 4; ++r) ml[r] = fmaxf(ml[r], __shfl_xor(ml[r], off, 16));

    float scl[4];
#pragma unroll
    for (int r = 0; r < 4; ++r) {
      float mn = fmaxf(mr[r], ml[r]);
      scl[r] = __expf(mr[r] - mn);
      mr[r] = mn;
    }
    float rs[4] = {0.f, 0.f, 0.f, 0.f};
#pragma unroll
    for (int c = 0; c < 4; ++c)
#pragma unroll
      for (int r = 0; r < 4; ++r) {
        float p = __expf(s[c][r] - mr[r]);
        s[c][r] = p;
        rs[r] += p;
      }
#pragma unroll
    for (int off = 1; off < 16; off <<= 1)
#pragma unroll
      for (int r = 0; r < 4; ++r) rs[r] += __shfl_xor(rs[r], off, 16);
#pragma unroll
    for (int r = 0; r < 4; ++r) lr[r] = lr[r] * scl[r] + rs[r];
#pragma unroll
    for (int c = 0; c < 4; ++c)
#pragma unroll
      for (int r = 0; r < 4; ++r) {
        O[c][r] *= scl[r];
        P[w * 16 + g * 4 + r][c * 16 + li] = bf16_rtn(s[c][r]);
      }
    __syncthreads();

#pragma unroll
    for (int ks = 0; ks < 2; ++ks) {
      bf16x8 pa = *(const bf16x8*)&P[w * 16 + li][ks * 32 + g * 8];
#pragma unroll
      for (int c = 0; c < 4; ++c) {
        bf16x8 vb = *(const bf16x8*)&vtb[(size_t)(c * 16 + li) * T + kb * 64 + ks * 32 + g * 8];
        O[c] = MFMA16(pa, vb, O[c]);
      }
    }
    __syncthreads();
  }

#pragma unroll
  for (int c = 0; c < 4; ++c)
#pragma unroll
    for (int r = 0; r < 4; ++r) {
      float v = O[c][r] / lr[r];
      size_t row = (size_t)(n * T + qb * 64 + w * 16 + g * 4 + r);
      out[row * E + h * HD + c * 16 + li] = bf16_rtn(v);
    }
}

// ---------------------------------------------------------------------------
extern "C" void kernel_launch(void* const* d_in, const int* in_sizes, int n_in,
                              void* d_out, int out_size, void* d_ws, size_t ws_size,
                              hipStream_t stream) {
  const float* kq = (const float*)d_in[0];
  const float* v = (const float*)d_in[1];
  const float* Wk = (const float*)d_in[2];
  const float* bk = (const float*)d_in[3];
  const float* Wq = (const float*)d_in[4];
  const float* bq = (const float*)d_in[5];
  const float* Wv = (const float*)d_in[6];
  const float* bv = (const float*)d_in[7];
  const float* W1 = (const float*)d_in[8];
  const float* b1 = (const float*)d_in[9];
  const float* W2 = (const float*)d_in[10];
  const float* b2 = (const float*)d_in[11];
  float* outp = (float*)d_out;

  char* ws = (char*)d_ws;
  // Region A (32MB): kq_hi, kq_lo, v_bf, vv -- dead after attention prep;
  // reused as FFN hidden h (32MB).
  u16* kq_hi = (u16*)(ws + 0);
  u16* kq_lo = (u16*)(ws + 8388608);
  u16* v_bf = (u16*)(ws + 16777216);
  u16* vv = (u16*)(ws + 25165824);
  u16* hbuf = (u16*)(ws + 0);  // aliases region A (32MB), used after attention
  u16* WkT_hi = (u16*)(ws + 33554432);
  u16* WkT_lo = (u16*)(ws + 35651584);
  u16* WqT_hi = (u16*)(ws + 37748736);
  u16* WqT_lo = (u16*)(ws + 39845888);
  u16* WvT = (u16*)(ws + 41943040);
  u16* W1T = (u16*)(ws + 44040192);
  u16* W2T = (u16*)(ws + 52428800);
  float* qf = (float*)(ws + 60817408);
  float* kf = (float*)(ws + 77594624);
  u16* VT = (u16*)(ws + 94371840);
  u16* attn_o = (u16*)(ws + 102760448);
  // total: 111,149,056 bytes

  // --- conversions ---
  k_split<<<4096, 256, 0, stream>>>(kq, kq_hi, kq_lo, (4096 * 1024) / 4);
  k_conv<<<4096, 256, 0, stream>>>(v, v_bf, (4096 * 1024) / 4);
  k_tconv<1><<<dim3(32, 32), 256, 0, stream>>>(Wk, WkT_hi, WkT_lo, 1024, 1024);
  k_tconv<1><<<dim3(32, 32), 256, 0, stream>>>(Wq, WqT_hi, WqT_lo, 1024, 1024);
  k_tconv<0><<<dim3(32, 32), 256, 0, stream>>>(Wv, WvT, nullptr, 1024, 1024);
  k_tconv<0><<<dim3(128, 32), 256, 0, stream>>>(W1, W1T, nullptr, 1024, 4096);
  k_tconv<0><<<dim3(32, 128), 256, 0, stream>>>(W2, W2T, nullptr, 4096, 1024);

  // --- projections (K, Q split-precision; V plain) ---
  k_gemm<1, 0, 0><<<dim3(8, 32), 256, 40960, stream>>>(kq_hi, kq_lo, WkT_hi, WkT_lo, bk, kf, 4096, 1024, 1024);
  k_gemm<1, 0, 0><<<dim3(8, 32), 256, 40960, stream>>>(kq_hi, kq_lo, WqT_hi, WqT_lo, bq, qf, 4096, 1024, 1024);
  k_gemm<0, 0, 1><<<dim3(8, 32), 256, 20480, stream>>>(v_bf, nullptr, WvT, nullptr, bv, vv, 4096, 1024, 1024);

  // --- V transpose to [n,h,d,T] ---
  k_t16<<<dim3(32, 64, 2), 256, 0, stream>>>(vv, VT, 2048, 1024);

  // --- attention ---
  k_attn<<<dim3(32, 16, 2), 256, 0, stream>>>(qf, kf, VT, attn_o);

  // --- FFN ---
  k_gemm<0, 1, 1><<<dim3(32, 32), 256, 20480, stream>>>(attn_o, nullptr, W1T, nullptr, b1, hbuf, 4096, 4096, 1024);
  k_gemm<0, 0, 0><<<dim3(8, 32), 256, 20480, stream>>>(hbuf, nullptr, W2T, nullptr, b2, outp, 4096, 1024, 4096);
}